// Round 1
// baseline (348.669 us; speedup 1.0000x reference)
//
#include <hip/hip_runtime.h>
#include <hip/hip_bf16.h>

typedef __hip_bfloat16 bf16;
typedef __attribute__((ext_vector_type(8))) short bf16x8;
typedef __attribute__((ext_vector_type(4))) float f32x4;

#define MFMA_BF16(a, b, c) __builtin_amdgcn_mfma_f32_16x16x32_bf16((a), (b), (c), 0, 0, 0)

#define B_   2
#define S_   2048
#define HID_ 2048
#define H_   16
#define HKV_ 4
#define D_   128

// ---------------------------------------------------------------- fp32 -> bf16
__global__ void cvt_f32_bf16(const float* __restrict__ src, bf16* __restrict__ dst, int n) {
  int i = (blockIdx.x * 256 + threadIdx.x) * 4;
  if (i >= n) return;
  float4 v = *reinterpret_cast<const float4*>(src + i);
  alignas(8) bf16 t[4];
  t[0] = __float2bfloat16(v.x);
  t[1] = __float2bfloat16(v.y);
  t[2] = __float2bfloat16(v.z);
  t[3] = __float2bfloat16(v.w);
  *reinterpret_cast<short4*>(dst + i) = *reinterpret_cast<const short4*>(t);
}

// ---------------------------------------------------------------- GEMM: C[M][N] = A[M][K] * B[N][K]^T
// 128x128 tile, BK=64, 256 threads (4 waves, each 64x64), global_load_lds staging.
template <int OUT_BF16>
__global__ __launch_bounds__(256) void gemm_bt(const bf16* __restrict__ A,
                                               const bf16* __restrict__ Bw,
                                               void* __restrict__ Cout,
                                               int M, int N, int K) {
  __shared__ bf16 As[128 * 64];
  __shared__ bf16 Bs[128 * 64];
  const int tid  = threadIdx.x;
  const int lane = tid & 63;
  const int w    = tid >> 6;
  const int wr   = w >> 1, wc = w & 1;
  const int ln15 = lane & 15, g = lane >> 4;
  const int m0 = blockIdx.y * 128, n0 = blockIdx.x * 128;

  f32x4 acc[4][4] = {};

  for (int kt = 0; kt < K; kt += 64) {
    __syncthreads();
#pragma unroll
    for (int r = 0; r < 4; r++) {
      int idx = r * 256 + tid;
      int row = idx >> 3;
      int col = (idx & 7) << 3;
      int ldsbase = (r * 256 + w * 64) * 8;  // elements (wave-uniform)
      __builtin_amdgcn_global_load_lds(
          (const __attribute__((address_space(1))) void*)(A + (size_t)(m0 + row) * K + kt + col),
          (__attribute__((address_space(3))) void*)(As + ldsbase), 16, 0, 0);
      __builtin_amdgcn_global_load_lds(
          (const __attribute__((address_space(1))) void*)(Bw + (size_t)(n0 + row) * K + kt + col),
          (__attribute__((address_space(3))) void*)(Bs + ldsbase), 16, 0, 0);
    }
    __syncthreads();
#pragma unroll
    for (int kk = 0; kk < 2; kk++) {
      bf16x8 af[4], bfr[4];
#pragma unroll
      for (int m = 0; m < 4; m++)
        af[m] = *reinterpret_cast<const bf16x8*>(&As[(wr * 64 + m * 16 + ln15) * 64 + kk * 32 + g * 8]);
#pragma unroll
      for (int n = 0; n < 4; n++)
        bfr[n] = *reinterpret_cast<const bf16x8*>(&Bs[(wc * 64 + n * 16 + ln15) * 64 + kk * 32 + g * 8]);
#pragma unroll
      for (int m = 0; m < 4; m++)
#pragma unroll
        for (int n = 0; n < 4; n++)
          acc[m][n] = MFMA_BF16(af[m], bfr[n], acc[m][n]);
    }
  }

  // epilogue: C row = m0 + wr*64 + m*16 + g*4 + r ; col = n0 + wc*64 + n*16 + ln15
#pragma unroll
  for (int m = 0; m < 4; m++)
#pragma unroll
    for (int n = 0; n < 4; n++)
#pragma unroll
      for (int r = 0; r < 4; r++) {
        int row = m0 + wr * 64 + m * 16 + g * 4 + r;
        int col = n0 + wc * 64 + n * 16 + ln15;
        if constexpr (OUT_BF16) {
          ((bf16*)Cout)[(size_t)row * N + col] = __float2bfloat16(acc[m][n][r]);
        } else {
          ((float*)Cout)[(size_t)row * N + col] = acc[m][n][r];
        }
      }
}

// ---------------------------------------------------------------- clip + RoPE + layout
// QKV row layout: [0..2047]=Q(h*128+d) [2048..2559]=K [2560..3071]=V
__global__ __launch_bounds__(256) void qkv_post(const bf16* __restrict__ QKV,
                                                const int* __restrict__ wpos,
                                                bf16* __restrict__ Qs,   // [B][H][S][D]
                                                bf16* __restrict__ Ks,   // [B][HKV][S][D]
                                                bf16* __restrict__ Vt) { // [B][HKV][D][S]
  const int row = blockIdx.x;  // b*S + s
  const int b = row >> 11, s = row & (S_ - 1);
  const int t = threadIdx.x;
  const bf16* R = QKV + (size_t)row * 3072;
  const float pos = (float)wpos[row];
  const float kln = 0.14391156831212787f;  // ln(10000)/64
  const float qscale = 0.08838834764831845f;  // 1/sqrt(128)

  // Q: 1024 rope pairs
  for (int p = t; p < 1024; p += 256) {
    int h = p >> 6, i = p & 63;
    float ang = pos * expf(-(float)i * kln);
    float sn, cs;
    sincosf(ang, &sn, &cs);
    float x1 = __bfloat162float(R[h * 128 + i]);
    float x2 = __bfloat162float(R[h * 128 + 64 + i]);
    x1 = fminf(fmaxf(x1, -8.f), 8.f);
    x2 = fminf(fmaxf(x2, -8.f), 8.f);
    float y1 = (x1 * cs - x2 * sn) * qscale;
    float y2 = (x2 * cs + x1 * sn) * qscale;
    size_t qb = ((size_t)(b * H_ + h) * S_ + s) * D_;
    Qs[qb + i]      = __float2bfloat16(y1);
    Qs[qb + 64 + i] = __float2bfloat16(y2);
  }
  // K: 256 rope pairs (one per thread)
  {
    int kh = t >> 6, i = t & 63;
    float ang = pos * expf(-(float)i * kln);
    float sn, cs;
    sincosf(ang, &sn, &cs);
    float x1 = __bfloat162float(R[2048 + kh * 128 + i]);
    float x2 = __bfloat162float(R[2048 + kh * 128 + 64 + i]);
    x1 = fminf(fmaxf(x1, -8.f), 8.f);
    x2 = fminf(fmaxf(x2, -8.f), 8.f);
    float y1 = x1 * cs - x2 * sn;
    float y2 = x2 * cs + x1 * sn;
    size_t kb = ((size_t)(b * HKV_ + kh) * S_ + s) * D_;
    Ks[kb + i]      = __float2bfloat16(y1);
    Ks[kb + 64 + i] = __float2bfloat16(y2);
  }
  // V: 512 elems, clip only, transposed store
  for (int e = t; e < 512; e += 256) {
    int kh = e >> 7, d = e & 127;
    float x = __bfloat162float(R[2560 + e]);
    x = fminf(fmaxf(x, -8.f), 8.f);
    Vt[((size_t)(b * HKV_ + kh) * D_ + d) * S_ + s] = __float2bfloat16(x);
  }
}

// ---------------------------------------------------------------- flash attention
// 1 wave per (b, h, 16-query tile). Swapped QK^T: S_t[key][query] = mfma(K, Q).
// PV computed as O^T[d][q] = mfma(Vt, P_t). P round-trips LDS to become B-fragment.
__global__ __launch_bounds__(64) void attn_fwd(const bf16* __restrict__ Qs,
                                               const bf16* __restrict__ Ks,
                                               const bf16* __restrict__ Vt,
                                               const int* __restrict__ seq,
                                               bf16* __restrict__ att) {  // [B][S][H*D]
  __shared__ bf16 Plds[16 * 32];  // [q][key]
  const int lane = threadIdx.x;
  const int ln15 = lane & 15, g = lane >> 4;
  const int bid = blockIdx.x;
  const int qt = bid & 127;          // S/16
  const int h  = (bid >> 7) & 15;
  const int b  = bid >> 11;
  const int kvh = h >> 2;            // G = 4
  const int q0 = qt * 16;
  const int qi = q0 + ln15;          // this lane's query (its MFMA column)
  const int* seqb = seq + b * S_;

  const bf16* Qrow = Qs + ((size_t)(b * H_ + h) * S_ + qi) * D_;
  bf16x8 qf[4];
#pragma unroll
  for (int c = 0; c < 4; c++)
    qf[c] = *reinterpret_cast<const bf16x8*>(Qrow + c * 32 + g * 8);

  const int sid_q = seqb[qi];
  const int sid0  = seqb[q0];
  int lo = 0, hi = q0;                       // first index of q0's sequence
  while (lo < hi) {
    int mid = (lo + hi) >> 1;
    if (seqb[mid] < sid0) lo = mid + 1; else hi = mid;
  }
  const int kstart = lo;

  const bf16* Kb = Ks + (size_t)(b * HKV_ + kvh) * S_ * D_;
  const bf16* Vb = Vt + (size_t)(b * HKV_ + kvh) * D_ * S_;

  float m = -1e30f, lsum = 0.f;
  f32x4 o[8] = {};

  for (int kb = kstart; kb <= q0 + 15; kb += 32) {
    f32x4 s0 = {0.f, 0.f, 0.f, 0.f}, s1 = {0.f, 0.f, 0.f, 0.f};
    const bf16* Kr0 = Kb + (size_t)min(kb + ln15, S_ - 1) * D_;
    const bf16* Kr1 = Kb + (size_t)min(kb + 16 + ln15, S_ - 1) * D_;
#pragma unroll
    for (int c = 0; c < 4; c++) {
      bf16x8 ka = *reinterpret_cast<const bf16x8*>(Kr0 + c * 32 + g * 8);
      s0 = MFMA_BF16(ka, qf[c], s0);
      bf16x8 kb2 = *reinterpret_cast<const bf16x8*>(Kr1 + c * 32 + g * 8);
      s1 = MFMA_BF16(kb2, qf[c], s1);
    }
    // mask + online softmax. lane holds keys kb+g*4+r (s0) and kb+16+g*4+r (s1) for query qi.
    float sc[8];
    float tmax = -1e30f;
#pragma unroll
    for (int r = 0; r < 4; r++) {
      int k0i = kb + g * 4 + r;
      int k1i = k0i + 16;
      float x0 = ((k0i <= qi) && (seqb[min(k0i, S_ - 1)] == sid_q)) ? s0[r] : -1e30f;
      float x1 = ((k1i <= qi) && (seqb[min(k1i, S_ - 1)] == sid_q)) ? s1[r] : -1e30f;
      sc[r] = x0;
      sc[4 + r] = x1;
      tmax = fmaxf(tmax, fmaxf(x0, x1));
    }
    tmax = fmaxf(tmax, __shfl_xor(tmax, 16));
    tmax = fmaxf(tmax, __shfl_xor(tmax, 32));
    float mn  = fmaxf(m, tmax);
    float fac = __expf(m - mn);
    float ps = 0.f;
    alignas(16) bf16 pb[8];
#pragma unroll
    for (int i2 = 0; i2 < 8; i2++) {
      float p = (sc[i2] < -1e29f) ? 0.f : __expf(sc[i2] - mn);
      ps += p;
      pb[i2] = __float2bfloat16(p);
    }
    ps += __shfl_xor(ps, 16);
    ps += __shfl_xor(ps, 32);
    lsum = lsum * fac + ps;
    m = mn;
#pragma unroll
    for (int t2 = 0; t2 < 8; t2++) o[t2] *= fac;

    // P -> LDS [q][key] so the PV B-fragment is one contiguous 16B read
    *reinterpret_cast<short4*>(&Plds[ln15 * 32 + g * 4])      = *reinterpret_cast<const short4*>(&pb[0]);
    *reinterpret_cast<short4*>(&Plds[ln15 * 32 + 16 + g * 4]) = *reinterpret_cast<const short4*>(&pb[4]);
    __syncthreads();
    bf16x8 pf = *reinterpret_cast<const bf16x8*>(&Plds[ln15 * 32 + g * 8]);
#pragma unroll
    for (int t2 = 0; t2 < 8; t2++) {
      bf16x8 vf = *reinterpret_cast<const bf16x8*>(Vb + (size_t)(t2 * 16 + ln15) * S_ + kb + g * 8);
      o[t2] = MFMA_BF16(vf, pf, o[t2]);
    }
    __syncthreads();
  }

  float inv = 1.f / lsum;
#pragma unroll
  for (int t2 = 0; t2 < 8; t2++)
#pragma unroll
    for (int r = 0; r < 4; r++) {
      int d = t2 * 16 + g * 4 + r;
      att[((size_t)(b * S_ + qi)) * (H_ * D_) + h * D_ + d] = __float2bfloat16(o[t2][r] * inv);
    }
}

// ---------------------------------------------------------------- launcher
extern "C" void kernel_launch(void* const* d_in, const int* in_sizes, int n_in,
                              void* d_out, int out_size, void* d_ws, size_t ws_size,
                              hipStream_t stream) {
  const float* hidden = (const float*)d_in[0];
  const int* wpos = (const int*)d_in[1];
  // d_in[2] = global_position_ids (unused by reference path)
  const int* seq = (const int*)d_in[3];
  const float* Wq = (const float*)d_in[4];
  const float* Wk = (const float*)d_in[5];
  const float* Wv = (const float*)d_in[6];
  const float* Wo = (const float*)d_in[7];

  char* ws = (char*)d_ws;
  // layout (bytes):
  //   [0,           16777216)  Xb  (hidden bf16)      -> reused as Qs
  //   [16777216,    29360128)  Wqkv bf16 [3072][2048]
  //   [29360128,    37748736)  Wo   bf16 [2048][2048]
  //   [37748736,    62914560)  QKV  bf16 [4096][3072] -> reused as att [4096][2048]
  //   [62914560,    67108864)  Ks   bf16 [B][HKV][S][D]
  //   [67108864,    71303168)  Vt   bf16 [B][HKV][D][S]  (+64B OOB slack)
  bf16* Xb   = (bf16*)(ws);
  bf16* Wqkv = (bf16*)(ws + 16777216);
  bf16* Wob  = (bf16*)(ws + 29360128);
  bf16* QKVb = (bf16*)(ws + 37748736);
  bf16* Ksb  = (bf16*)(ws + 62914560);
  bf16* Vtb  = (bf16*)(ws + 67108864);
  bf16* Qsb  = Xb;
  bf16* attb = QKVb;

  cvt_f32_bf16<<<dim3(8192), dim3(256), 0, stream>>>(hidden, Xb, 8388608);
  cvt_f32_bf16<<<dim3(4096), dim3(256), 0, stream>>>(Wq, Wqkv, 4194304);
  cvt_f32_bf16<<<dim3(1024), dim3(256), 0, stream>>>(Wk, Wqkv + 4194304, 1048576);
  cvt_f32_bf16<<<dim3(1024), dim3(256), 0, stream>>>(Wv, Wqkv + 5242880, 1048576);
  cvt_f32_bf16<<<dim3(4096), dim3(256), 0, stream>>>(Wo, Wob, 4194304);

  gemm_bt<1><<<dim3(24, 32), dim3(256), 0, stream>>>(Xb, Wqkv, (void*)QKVb, 4096, 3072, 2048);

  qkv_post<<<dim3(4096), dim3(256), 0, stream>>>(QKVb, wpos, Qsb, Ksb, Vtb);

  attn_fwd<<<dim3(4096), dim3(64), 0, stream>>>(Qsb, Ksb, Vtb, seq, attb);

  gemm_bt<0><<<dim3(16, 32), dim3(256), 0, stream>>>(attb, Wob, d_out, 4096, 2048, 2048);
}

// Round 2
// 318.586 us; speedup vs baseline: 1.0944x; 1.0944x over previous
//
#include <hip/hip_runtime.h>
#include <hip/hip_bf16.h>

typedef __hip_bfloat16 bf16;
typedef __attribute__((ext_vector_type(8))) short bf16x8;
typedef __attribute__((ext_vector_type(4))) float f32x4;

#define MFMA_BF16(a, b, c) __builtin_amdgcn_mfma_f32_16x16x32_bf16((a), (b), (c), 0, 0, 0)

#define B_   2
#define S_   2048
#define HID_ 2048
#define H_   16
#define HKV_ 4
#define D_   128

// ---------------------------------------------------------------- fp32 -> bf16
__global__ void cvt_f32_bf16(const float* __restrict__ src, bf16* __restrict__ dst, int n) {
  int i = (blockIdx.x * 256 + threadIdx.x) * 4;
  if (i >= n) return;
  float4 v = *reinterpret_cast<const float4*>(src + i);
  alignas(8) bf16 t[4];
  t[0] = __float2bfloat16(v.x);
  t[1] = __float2bfloat16(v.y);
  t[2] = __float2bfloat16(v.z);
  t[3] = __float2bfloat16(v.w);
  *reinterpret_cast<short4*>(dst + i) = *reinterpret_cast<const short4*>(t);
}

// ---------------------------------------------------------------- per-position sequence start
// sstart[b*S+s] = first index i in batch b with seq[i] == seq[s] (seq is sorted per batch).
__global__ void seq_start(const int* __restrict__ seq, int* __restrict__ sstart) {
  int t = blockIdx.x * 256 + threadIdx.x;  // 0..8191
  int b = t >> 11, s = t & (S_ - 1);
  const int* sb = seq + b * S_;
  int sid = sb[s];
  int lo = 0, hi = s;
  while (lo < hi) {
    int mid = (lo + hi) >> 1;
    if (sb[mid] < sid) lo = mid + 1; else hi = mid;
  }
  sstart[t] = lo;
}

// ---------------------------------------------------------------- GEMM: C[M][N] = A[M][K] * B[N][K]^T
// 128x128 tile, BK=64, 256 threads (4 waves, each 64x64), global_load_lds staging.
template <int OUT_BF16>
__global__ __launch_bounds__(256) void gemm_bt(const bf16* __restrict__ A,
                                               const bf16* __restrict__ Bw,
                                               void* __restrict__ Cout,
                                               int M, int N, int K) {
  __shared__ bf16 As[128 * 64];
  __shared__ bf16 Bs[128 * 64];
  const int tid  = threadIdx.x;
  const int lane = tid & 63;
  const int w    = tid >> 6;
  const int wr   = w >> 1, wc = w & 1;
  const int ln15 = lane & 15, g = lane >> 4;
  const int m0 = blockIdx.y * 128, n0 = blockIdx.x * 128;

  f32x4 acc[4][4] = {};

  for (int kt = 0; kt < K; kt += 64) {
    __syncthreads();
#pragma unroll
    for (int r = 0; r < 4; r++) {
      int idx = r * 256 + tid;
      int row = idx >> 3;
      int col = (idx & 7) << 3;
      int ldsbase = (r * 256 + w * 64) * 8;  // elements (wave-uniform)
      __builtin_amdgcn_global_load_lds(
          (const __attribute__((address_space(1))) void*)(A + (size_t)(m0 + row) * K + kt + col),
          (__attribute__((address_space(3))) void*)(As + ldsbase), 16, 0, 0);
      __builtin_amdgcn_global_load_lds(
          (const __attribute__((address_space(1))) void*)(Bw + (size_t)(n0 + row) * K + kt + col),
          (__attribute__((address_space(3))) void*)(Bs + ldsbase), 16, 0, 0);
    }
    __syncthreads();
#pragma unroll
    for (int kk = 0; kk < 2; kk++) {
      bf16x8 af[4], bfr[4];
#pragma unroll
      for (int m = 0; m < 4; m++)
        af[m] = *reinterpret_cast<const bf16x8*>(&As[(wr * 64 + m * 16 + ln15) * 64 + kk * 32 + g * 8]);
#pragma unroll
      for (int n = 0; n < 4; n++)
        bfr[n] = *reinterpret_cast<const bf16x8*>(&Bs[(wc * 64 + n * 16 + ln15) * 64 + kk * 32 + g * 8]);
#pragma unroll
      for (int m = 0; m < 4; m++)
#pragma unroll
        for (int n = 0; n < 4; n++)
          acc[m][n] = MFMA_BF16(af[m], bfr[n], acc[m][n]);
    }
  }

  // epilogue: C row = m0 + wr*64 + m*16 + g*4 + r ; col = n0 + wc*64 + n*16 + ln15
#pragma unroll
  for (int m = 0; m < 4; m++)
#pragma unroll
    for (int n = 0; n < 4; n++)
#pragma unroll
      for (int r = 0; r < 4; r++) {
        int row = m0 + wr * 64 + m * 16 + g * 4 + r;
        int col = n0 + wc * 64 + n * 16 + ln15;
        if constexpr (OUT_BF16) {
          ((bf16*)Cout)[(size_t)row * N + col] = __float2bfloat16(acc[m][n][r]);
        } else {
          ((float*)Cout)[(size_t)row * N + col] = acc[m][n][r];
        }
      }
}

// ---------------------------------------------------------------- clip + RoPE + layout
// QKV row layout: [0..2047]=Q(h*128+d) [2048..2559]=K [2560..3071]=V
__global__ __launch_bounds__(256) void qkv_post(const bf16* __restrict__ QKV,
                                                const int* __restrict__ wpos,
                                                bf16* __restrict__ Qs,   // [B][H][S][D]
                                                bf16* __restrict__ Ks,   // [B][HKV][S][D]
                                                bf16* __restrict__ Vt) { // [B][HKV][D][S]
  const int row = blockIdx.x;  // b*S + s
  const int b = row >> 11, s = row & (S_ - 1);
  const int t = threadIdx.x;
  const bf16* R = QKV + (size_t)row * 3072;
  const float pos = (float)wpos[row];
  const float kln = 0.14391156831212787f;  // ln(10000)/64
  const float qscale = 0.08838834764831845f;  // 1/sqrt(128)

  // Q: 1024 rope pairs
  for (int p = t; p < 1024; p += 256) {
    int h = p >> 6, i = p & 63;
    float ang = pos * expf(-(float)i * kln);
    float sn, cs;
    sincosf(ang, &sn, &cs);
    float x1 = __bfloat162float(R[h * 128 + i]);
    float x2 = __bfloat162float(R[h * 128 + 64 + i]);
    x1 = fminf(fmaxf(x1, -8.f), 8.f);
    x2 = fminf(fmaxf(x2, -8.f), 8.f);
    float y1 = (x1 * cs - x2 * sn) * qscale;
    float y2 = (x2 * cs + x1 * sn) * qscale;
    size_t qb = ((size_t)(b * H_ + h) * S_ + s) * D_;
    Qs[qb + i]      = __float2bfloat16(y1);
    Qs[qb + 64 + i] = __float2bfloat16(y2);
  }
  // K: 256 rope pairs (one per thread)
  {
    int kh = t >> 6, i = t & 63;
    float ang = pos * expf(-(float)i * kln);
    float sn, cs;
    sincosf(ang, &sn, &cs);
    float x1 = __bfloat162float(R[2048 + kh * 128 + i]);
    float x2 = __bfloat162float(R[2048 + kh * 128 + 64 + i]);
    x1 = fminf(fmaxf(x1, -8.f), 8.f);
    x2 = fminf(fmaxf(x2, -8.f), 8.f);
    float y1 = x1 * cs - x2 * sn;
    float y2 = x2 * cs + x1 * sn;
    size_t kb = ((size_t)(b * HKV_ + kh) * S_ + s) * D_;
    Ks[kb + i]      = __float2bfloat16(y1);
    Ks[kb + 64 + i] = __float2bfloat16(y2);
  }
  // V: 512 elems, clip only, transposed store
  for (int e = t; e < 512; e += 256) {
    int kh = e >> 7, d = e & 127;
    float x = __bfloat162float(R[2560 + e]);
    x = fminf(fmaxf(x, -8.f), 8.f);
    Vt[((size_t)(b * HKV_ + kh) * D_ + d) * S_ + s] = __float2bfloat16(x);
  }
}

// ---------------------------------------------------------------- flash attention
// 1 wave per (b, h, 16-query tile). Swapped QK^T: S_t[key][query] = mfma(K, Q).
// Mask via precomputed per-query sequence start (seq sorted): k valid iff sQ<=k<=qi.
// K double-buffered in registers; V issued early; no __syncthreads (1-wave block,
// DS ops are in-order within a wave).
__global__ __launch_bounds__(64) void attn_fwd(const bf16* __restrict__ Qs,
                                               const bf16* __restrict__ Ks,
                                               const bf16* __restrict__ Vt,
                                               const int* __restrict__ sstart,
                                               bf16* __restrict__ att) {  // [B][S][H*D]
  __shared__ bf16 Plds[16 * 32];  // [q][key]
  const int lane = threadIdx.x;
  const int ln15 = lane & 15, g = lane >> 4;
  const int bid = blockIdx.x;
  const int qt = bid & 127;          // S/16
  const int h  = (bid >> 7) & 15;
  const int b  = bid >> 11;
  const int kvh = h >> 2;            // G = 4
  const int q0 = qt * 16;
  const int qi = q0 + ln15;          // this lane's query (its MFMA column)

  const bf16* Qrow = Qs + ((size_t)(b * H_ + h) * S_ + qi) * D_;
  bf16x8 qf[4];
#pragma unroll
  for (int c = 0; c < 4; c++)
    qf[c] = *reinterpret_cast<const bf16x8*>(Qrow + c * 32 + g * 8);

  const int sQ = sstart[b * S_ + qi];                   // per-lane seq start
  const int kstart = __builtin_amdgcn_readfirstlane(sQ); // lane0 has qi=q0
  const int kend = q0 + 15;

  const bf16* Kb = Ks + (size_t)(b * HKV_ + kvh) * S_ * D_;
  const bf16* Vb = Vt + (size_t)(b * HKV_ + kvh) * D_ * S_;

  float m = -1e30f, lsum = 0.f;
  f32x4 o[8] = {};

  bf16x8 kA[8], kB[8];

  auto loadK = [&](bf16x8 (&dst)[8], int kbase) {
    const bf16* r0 = Kb + (size_t)min(kbase + ln15, S_ - 1) * D_;
    const bf16* r1 = Kb + (size_t)min(kbase + 16 + ln15, S_ - 1) * D_;
#pragma unroll
    for (int c = 0; c < 4; c++) {
      dst[c]     = *reinterpret_cast<const bf16x8*>(r0 + c * 32 + g * 8);
      dst[4 + c] = *reinterpret_cast<const bf16x8*>(r1 + c * 32 + g * 8);
    }
  };

  auto step = [&](bf16x8 (&cur)[8], bf16x8 (&nxt)[8], int kb) {
    // V frags for this tile: issue early, consume at the end
    bf16x8 vf[8];
#pragma unroll
    for (int t2 = 0; t2 < 8; t2++)
      vf[t2] = *reinterpret_cast<const bf16x8*>(Vb + (size_t)(t2 * 16 + ln15) * S_ + kb + g * 8);
    // prefetch next K tile (clamped rows -> always in-bounds)
    loadK(nxt, kb + 32);

    f32x4 s0 = {0.f, 0.f, 0.f, 0.f}, s1 = {0.f, 0.f, 0.f, 0.f};
#pragma unroll
    for (int c = 0; c < 4; c++) {
      s0 = MFMA_BF16(cur[c], qf[c], s0);
      s1 = MFMA_BF16(cur[4 + c], qf[c], s1);
    }

    // mask + online softmax. lane holds keys kb+g*4+r (s0) and +16 (s1) for query qi.
    float sc[8];
    float tmax = -1e30f;
#pragma unroll
    for (int r = 0; r < 4; r++) {
      int k0i = kb + g * 4 + r;
      int k1i = k0i + 16;
      float x0 = (k0i >= sQ && k0i <= qi) ? s0[r] : -1e30f;
      float x1 = (k1i >= sQ && k1i <= qi) ? s1[r] : -1e30f;
      sc[r] = x0;
      sc[4 + r] = x1;
      tmax = fmaxf(tmax, fmaxf(x0, x1));
    }
    tmax = fmaxf(tmax, __shfl_xor(tmax, 16));
    tmax = fmaxf(tmax, __shfl_xor(tmax, 32));
    float mn  = fmaxf(m, tmax);
    float fac = __expf(m - mn);
    float ps = 0.f;
    alignas(16) bf16 pb[8];
#pragma unroll
    for (int i2 = 0; i2 < 8; i2++) {
      float p = (sc[i2] < -1e29f) ? 0.f : __expf(sc[i2] - mn);
      ps += p;
      pb[i2] = __float2bfloat16(p);
    }
    ps += __shfl_xor(ps, 16);
    ps += __shfl_xor(ps, 32);
    lsum = lsum * fac + ps;
    m = mn;
#pragma unroll
    for (int t2 = 0; t2 < 8; t2++) o[t2] *= fac;

    // P -> LDS [q][key]: cross-lane exchange within the single wave.
    *reinterpret_cast<short4*>(&Plds[ln15 * 32 + g * 4])      = *reinterpret_cast<const short4*>(&pb[0]);
    *reinterpret_cast<short4*>(&Plds[ln15 * 32 + 16 + g * 4]) = *reinterpret_cast<const short4*>(&pb[4]);
    __builtin_amdgcn_wave_barrier();
    bf16x8 pf = *reinterpret_cast<const bf16x8*>(&Plds[ln15 * 32 + g * 8]);
#pragma unroll
    for (int t2 = 0; t2 < 8; t2++)
      o[t2] = MFMA_BF16(vf[t2], pf, o[t2]);
    __builtin_amdgcn_wave_barrier();
  };

  int kb = kstart;
  loadK(kA, kb);
  while (true) {
    step(kA, kB, kb); kb += 32; if (kb > kend) break;
    step(kB, kA, kb); kb += 32; if (kb > kend) break;
  }

  float inv = 1.f / lsum;
#pragma unroll
  for (int t2 = 0; t2 < 8; t2++)
#pragma unroll
    for (int r = 0; r < 4; r++) {
      int d = t2 * 16 + g * 4 + r;
      att[((size_t)(b * S_ + qi)) * (H_ * D_) + h * D_ + d] = __float2bfloat16(o[t2][r] * inv);
    }
}

// ---------------------------------------------------------------- launcher
extern "C" void kernel_launch(void* const* d_in, const int* in_sizes, int n_in,
                              void* d_out, int out_size, void* d_ws, size_t ws_size,
                              hipStream_t stream) {
  const float* hidden = (const float*)d_in[0];
  const int* wpos = (const int*)d_in[1];
  // d_in[2] = global_position_ids (unused by reference path)
  const int* seq = (const int*)d_in[3];
  const float* Wq = (const float*)d_in[4];
  const float* Wk = (const float*)d_in[5];
  const float* Wv = (const float*)d_in[6];
  const float* Wo = (const float*)d_in[7];

  char* ws = (char*)d_ws;
  // layout (bytes):
  //   [0,           16777216)  Xb  (hidden bf16)      -> reused as Qs
  //   [16777216,    29360128)  Wqkv bf16 [3072][2048]
  //   [29360128,    37748736)  Wo   bf16 [2048][2048]
  //   [37748736,    62914560)  QKV  bf16 [4096][3072] -> reused as att [4096][2048]
  //   [62914560,    67108864)  Ks   bf16 [B][HKV][S][D]
  //   [67108864,    71303168)  Vt   bf16 [B][HKV][D][S]
  //   [71303168,    71335936)  sstart int32 [B][S]
  bf16* Xb   = (bf16*)(ws);
  bf16* Wqkv = (bf16*)(ws + 16777216);
  bf16* Wob  = (bf16*)(ws + 29360128);
  bf16* QKVb = (bf16*)(ws + 37748736);
  bf16* Ksb  = (bf16*)(ws + 62914560);
  bf16* Vtb  = (bf16*)(ws + 67108864);
  int*  sst  = (int*)(ws + 71303168);
  bf16* Qsb  = Xb;
  bf16* attb = QKVb;

  cvt_f32_bf16<<<dim3(8192), dim3(256), 0, stream>>>(hidden, Xb, 8388608);
  cvt_f32_bf16<<<dim3(4096), dim3(256), 0, stream>>>(Wq, Wqkv, 4194304);
  cvt_f32_bf16<<<dim3(1024), dim3(256), 0, stream>>>(Wk, Wqkv + 4194304, 1048576);
  cvt_f32_bf16<<<dim3(1024), dim3(256), 0, stream>>>(Wv, Wqkv + 5242880, 1048576);
  cvt_f32_bf16<<<dim3(4096), dim3(256), 0, stream>>>(Wo, Wob, 4194304);
  seq_start<<<dim3(32), dim3(256), 0, stream>>>(seq, sst);

  gemm_bt<1><<<dim3(24, 32), dim3(256), 0, stream>>>(Xb, Wqkv, (void*)QKVb, 4096, 3072, 2048);

  qkv_post<<<dim3(4096), dim3(256), 0, stream>>>(QKVb, wpos, Qsb, Ksb, Vtb);

  attn_fwd<<<dim3(4096), dim3(64), 0, stream>>>(Qsb, Ksb, Vtb, sst, attb);

  gemm_bt<0><<<dim3(16, 32), dim3(256), 0, stream>>>(attb, Wob, d_out, 4096, 2048, 2048);
}

// Round 3
// 221.599 us; speedup vs baseline: 1.5734x; 1.4377x over previous
//
#include <hip/hip_runtime.h>
#include <hip/hip_bf16.h>

typedef __hip_bfloat16 bf16;
typedef __attribute__((ext_vector_type(8))) short bf16x8;
typedef __attribute__((ext_vector_type(4))) float f32x4;

#define MFMA_BF16(a, b, c) __builtin_amdgcn_mfma_f32_16x16x32_bf16((a), (b), (c), 0, 0, 0)

#define B_   2
#define S_   2048
#define HID_ 2048
#define H_   16
#define HKV_ 4
#define D_   128

#define GLOAD_LDS(gptr, lptr) \
  __builtin_amdgcn_global_load_lds((const __attribute__((address_space(1))) void*)(gptr), \
                                   (__attribute__((address_space(3))) void*)(lptr), 16, 0, 0)

// ---------------------------------------------------------------- fp32 -> bf16
__global__ void cvt_f32_bf16(const float* __restrict__ src, bf16* __restrict__ dst, int n) {
  int i = (blockIdx.x * 256 + threadIdx.x) * 4;
  if (i >= n) return;
  float4 v = *reinterpret_cast<const float4*>(src + i);
  alignas(8) bf16 t[4];
  t[0] = __float2bfloat16(v.x);
  t[1] = __float2bfloat16(v.y);
  t[2] = __float2bfloat16(v.z);
  t[3] = __float2bfloat16(v.w);
  *reinterpret_cast<short4*>(dst + i) = *reinterpret_cast<const short4*>(t);
}

// ---------------------------------------------------------------- per-position sequence start
__global__ void seq_start(const int* __restrict__ seq, int* __restrict__ sstart) {
  int t = blockIdx.x * 256 + threadIdx.x;  // 0..8191
  int b = t >> 11, s = t & (S_ - 1);
  const int* sb = seq + b * S_;
  int sid = sb[s];
  int lo = 0, hi = s;
  while (lo < hi) {
    int mid = (lo + hi) >> 1;
    if (sb[mid] < sid) lo = mid + 1; else hi = mid;
  }
  sstart[t] = lo;
}

// ---------------------------------------------------------------- GEMM: C[M][N] = A[M][K] * B[N][K]^T
template <int OUT_BF16>
__global__ __launch_bounds__(256) void gemm_bt(const bf16* __restrict__ A,
                                               const bf16* __restrict__ Bw,
                                               void* __restrict__ Cout,
                                               int M, int N, int K) {
  __shared__ bf16 As[128 * 64];
  __shared__ bf16 Bs[128 * 64];
  const int tid  = threadIdx.x;
  const int lane = tid & 63;
  const int w    = tid >> 6;
  const int wr   = w >> 1, wc = w & 1;
  const int ln15 = lane & 15, g = lane >> 4;
  const int m0 = blockIdx.y * 128, n0 = blockIdx.x * 128;

  f32x4 acc[4][4] = {};

  for (int kt = 0; kt < K; kt += 64) {
    __syncthreads();
#pragma unroll
    for (int r = 0; r < 4; r++) {
      int idx = r * 256 + tid;
      int row = idx >> 3;
      int col = (idx & 7) << 3;
      int ldsbase = (r * 256 + w * 64) * 8;
      GLOAD_LDS(A + (size_t)(m0 + row) * K + kt + col, As + ldsbase);
      GLOAD_LDS(Bw + (size_t)(n0 + row) * K + kt + col, Bs + ldsbase);
    }
    __syncthreads();
#pragma unroll
    for (int kk = 0; kk < 2; kk++) {
      bf16x8 af[4], bfr[4];
#pragma unroll
      for (int m = 0; m < 4; m++)
        af[m] = *reinterpret_cast<const bf16x8*>(&As[(wr * 64 + m * 16 + ln15) * 64 + kk * 32 + g * 8]);
#pragma unroll
      for (int n = 0; n < 4; n++)
        bfr[n] = *reinterpret_cast<const bf16x8*>(&Bs[(wc * 64 + n * 16 + ln15) * 64 + kk * 32 + g * 8]);
#pragma unroll
      for (int m = 0; m < 4; m++)
#pragma unroll
        for (int n = 0; n < 4; n++)
          acc[m][n] = MFMA_BF16(af[m], bfr[n], acc[m][n]);
    }
  }

#pragma unroll
  for (int m = 0; m < 4; m++)
#pragma unroll
    for (int n = 0; n < 4; n++)
#pragma unroll
      for (int r = 0; r < 4; r++) {
        int row = m0 + wr * 64 + m * 16 + g * 4 + r;
        int col = n0 + wc * 64 + n * 16 + ln15;
        if constexpr (OUT_BF16) {
          ((bf16*)Cout)[(size_t)row * N + col] = __float2bfloat16(acc[m][n][r]);
        } else {
          ((float*)Cout)[(size_t)row * N + col] = acc[m][n][r];
        }
      }
}

// ---------------------------------------------------------------- clip + RoPE + layout
__global__ __launch_bounds__(256) void qkv_post(const bf16* __restrict__ QKV,
                                                const int* __restrict__ wpos,
                                                bf16* __restrict__ Qs,   // [B][H][S][D]
                                                bf16* __restrict__ Ks,   // [B][HKV][S][D]
                                                bf16* __restrict__ Vt) { // [B][HKV][D][S]
  const int row = blockIdx.x;  // b*S + s
  const int b = row >> 11, s = row & (S_ - 1);
  const int t = threadIdx.x;
  const bf16* R = QKV + (size_t)row * 3072;
  const float pos = (float)wpos[row];
  const float kln = 0.14391156831212787f;   // ln(10000)/64
  const float qscale = 0.08838834764831845f; // 1/sqrt(128)

  for (int p = t; p < 1024; p += 256) {
    int h = p >> 6, i = p & 63;
    float ang = pos * expf(-(float)i * kln);
    float sn, cs;
    sincosf(ang, &sn, &cs);
    float x1 = __bfloat162float(R[h * 128 + i]);
    float x2 = __bfloat162float(R[h * 128 + 64 + i]);
    x1 = fminf(fmaxf(x1, -8.f), 8.f);
    x2 = fminf(fmaxf(x2, -8.f), 8.f);
    float y1 = (x1 * cs - x2 * sn) * qscale;
    float y2 = (x2 * cs + x1 * sn) * qscale;
    size_t qb = ((size_t)(b * H_ + h) * S_ + s) * D_;
    Qs[qb + i]      = __float2bfloat16(y1);
    Qs[qb + 64 + i] = __float2bfloat16(y2);
  }
  {
    int kh = t >> 6, i = t & 63;
    float ang = pos * expf(-(float)i * kln);
    float sn, cs;
    sincosf(ang, &sn, &cs);
    float x1 = __bfloat162float(R[2048 + kh * 128 + i]);
    float x2 = __bfloat162float(R[2048 + kh * 128 + 64 + i]);
    x1 = fminf(fmaxf(x1, -8.f), 8.f);
    x2 = fminf(fmaxf(x2, -8.f), 8.f);
    float y1 = x1 * cs - x2 * sn;
    float y2 = x2 * cs + x1 * sn;
    size_t kb = ((size_t)(b * HKV_ + kh) * S_ + s) * D_;
    Ks[kb + i]      = __float2bfloat16(y1);
    Ks[kb + 64 + i] = __float2bfloat16(y2);
  }
  for (int e = t; e < 512; e += 256) {
    int kh = e >> 7, d = e & 127;
    float x = __bfloat162float(R[2560 + e]);
    x = fminf(fmaxf(x, -8.f), 8.f);
    Vt[((size_t)(b * HKV_ + kh) * D_ + d) * S_ + s] = __float2bfloat16(x);
  }
}

// ---------------------------------------------------------------- flash attention
// Block = 4 waves = the 4 heads of one KV group, same (b, 16-query tile).
// K[32][128] + V^T[128][32] double-buffered in LDS via global_load_lds,
// XOR-swizzled (source-side pre-swizzle; linear LDS dest per rule).
// Swapped QK^T (mfma(K,Q)); per-wave softmax + P LDS exchange (wave-local).
__global__ __launch_bounds__(256) void attn_fwd(const bf16* __restrict__ Qs,
                                                const bf16* __restrict__ Ks,
                                                const bf16* __restrict__ Vt,
                                                const int* __restrict__ sstart,
                                                bf16* __restrict__ att) {  // [B][S][H*D]
  __shared__ bf16 Kl[2][32 * 128];   // slot(16B) s=row*16+c holds K[row][(c^(row&15))*8..+7]
  __shared__ bf16 Vl[2][128 * 32];   // slot s=d*4+c holds Vt[d][kb+((c^(d&3))*8)..+7]
  __shared__ bf16 Plds[4][16 * 32];

  const int tid = threadIdx.x;
  const int lane = tid & 63, w = tid >> 6;
  const int ln15 = lane & 15, g = lane >> 4;

  // XCD-contiguous swizzle: each XCD owns all 128 q-tiles of one (b,kvh)
  const int wg = ((blockIdx.x & 7) << 7) | (blockIdx.x >> 3);
  const int qt  = wg & 127;
  const int kvh = (wg >> 7) & 3;
  const int b   = wg >> 9;
  const int h   = kvh * 4 + w;
  const int q0  = qt * 16;
  const int qi  = q0 + ln15;

  const bf16* Qrow = Qs + ((size_t)(b * H_ + h) * S_ + qi) * D_;
  bf16x8 qf[4];
#pragma unroll
  for (int c = 0; c < 4; c++)
    qf[c] = *reinterpret_cast<const bf16x8*>(Qrow + c * 32 + g * 8);

  const int sQ = sstart[b * S_ + qi];
  const int kstart = __builtin_amdgcn_readfirstlane(__shfl(sQ, 0));
  const int kend = q0 + 15;

  const bf16* Kb = Ks + (size_t)(b * HKV_ + kvh) * S_ * D_;
  const bf16* Vb = Vt + (size_t)(b * HKV_ + kvh) * D_ * S_;

  auto stage = [&](int buf, int kb) {
#pragma unroll
    for (int p = 0; p < 2; p++) {
      int slot = p * 256 + tid;
      int row = slot >> 4;
      int cs = (slot & 15) ^ (row & 15);
      int gr = min(kb + row, S_ - 1);
      GLOAD_LDS(Kb + (size_t)gr * D_ + cs * 8, &Kl[buf][(p * 256 + w * 64) * 8]);
    }
#pragma unroll
    for (int p = 0; p < 2; p++) {
      int slot = p * 256 + tid;
      int d = slot >> 2, c = slot & 3;
      int cs = c ^ (d & 3);
      int gcol = min(kb + cs * 8, S_ - 8);
      GLOAD_LDS(Vb + (size_t)d * S_ + gcol, &Vl[buf][(p * 256 + w * 64) * 8]);
    }
  };

  float m = -1e30f, lsum = 0.f;
  f32x4 o[8] = {};

  stage(0, kstart);
  int buf = 0;
  for (int kb = kstart; kb <= kend; kb += 32) {
    __syncthreads();                       // staged tile ready; other buffer free
    if (kb + 32 <= kend) stage(buf ^ 1, kb + 32);

    // K frags from LDS (swizzled read)
    bf16x8 kf0[4], kf1[4];
#pragma unroll
    for (int c = 0; c < 4; c++) {
      kf0[c] = *reinterpret_cast<const bf16x8*>(&Kl[buf][ln15 * 128 + (((c * 4 + g) ^ ln15) << 3)]);
      kf1[c] = *reinterpret_cast<const bf16x8*>(&Kl[buf][(16 + ln15) * 128 + (((c * 4 + g) ^ ln15) << 3)]);
    }
    f32x4 s0 = {0.f, 0.f, 0.f, 0.f}, s1 = {0.f, 0.f, 0.f, 0.f};
#pragma unroll
    for (int c = 0; c < 4; c++) {
      s0 = MFMA_BF16(kf0[c], qf[c], s0);
      s1 = MFMA_BF16(kf1[c], qf[c], s1);
    }

    // mask + online softmax (lane: query qi, keys kb+g*4+r and +16)
    float sc[8];
    float tmax = -1e30f;
#pragma unroll
    for (int r = 0; r < 4; r++) {
      int k0i = kb + g * 4 + r;
      int k1i = k0i + 16;
      float x0 = (k0i >= sQ && k0i <= qi) ? s0[r] : -1e30f;
      float x1 = (k1i >= sQ && k1i <= qi) ? s1[r] : -1e30f;
      sc[r] = x0;
      sc[4 + r] = x1;
      tmax = fmaxf(tmax, fmaxf(x0, x1));
    }
    tmax = fmaxf(tmax, __shfl_xor(tmax, 16));
    tmax = fmaxf(tmax, __shfl_xor(tmax, 32));
    float mn  = fmaxf(m, tmax);
    float fac = __expf(m - mn);
    float ps = 0.f;
    alignas(16) bf16 pb[8];
#pragma unroll
    for (int i2 = 0; i2 < 8; i2++) {
      float p = (sc[i2] < -1e29f) ? 0.f : __expf(sc[i2] - mn);
      ps += p;
      pb[i2] = __float2bfloat16(p);
    }
    ps += __shfl_xor(ps, 16);
    ps += __shfl_xor(ps, 32);
    lsum = lsum * fac + ps;
    m = mn;
#pragma unroll
    for (int t2 = 0; t2 < 8; t2++) o[t2] *= fac;

    // P exchange (wave-local LDS region)
    *reinterpret_cast<short4*>(&Plds[w][ln15 * 32 + g * 4])      = *reinterpret_cast<const short4*>(&pb[0]);
    *reinterpret_cast<short4*>(&Plds[w][ln15 * 32 + 16 + g * 4]) = *reinterpret_cast<const short4*>(&pb[4]);
    __builtin_amdgcn_wave_barrier();
    bf16x8 pf = *reinterpret_cast<const bf16x8*>(&Plds[w][ln15 * 32 + g * 8]);

    // PV from LDS V^T (swizzled read)
#pragma unroll
    for (int t2 = 0; t2 < 8; t2++) {
      int d = t2 * 16 + ln15;
      bf16x8 vf = *reinterpret_cast<const bf16x8*>(&Vl[buf][d * 32 + ((g ^ (ln15 & 3)) << 3)]);
      o[t2] = MFMA_BF16(vf, pf, o[t2]);
    }
    __builtin_amdgcn_wave_barrier();
    buf ^= 1;
  }

  float inv = 1.f / lsum;
#pragma unroll
  for (int t2 = 0; t2 < 8; t2++)
#pragma unroll
    for (int r = 0; r < 4; r++) {
      int d = t2 * 16 + g * 4 + r;
      att[((size_t)(b * S_ + qi)) * (H_ * D_) + h * D_ + d] = __float2bfloat16(o[t2][r] * inv);
    }
}

// ---------------------------------------------------------------- launcher
extern "C" void kernel_launch(void* const* d_in, const int* in_sizes, int n_in,
                              void* d_out, int out_size, void* d_ws, size_t ws_size,
                              hipStream_t stream) {
  const float* hidden = (const float*)d_in[0];
  const int* wpos = (const int*)d_in[1];
  const int* seq = (const int*)d_in[3];
  const float* Wq = (const float*)d_in[4];
  const float* Wk = (const float*)d_in[5];
  const float* Wv = (const float*)d_in[6];
  const float* Wo = (const float*)d_in[7];

  char* ws = (char*)d_ws;
  bf16* Xb   = (bf16*)(ws);
  bf16* Wqkv = (bf16*)(ws + 16777216);
  bf16* Wob  = (bf16*)(ws + 29360128);
  bf16* QKVb = (bf16*)(ws + 37748736);
  bf16* Ksb  = (bf16*)(ws + 62914560);
  bf16* Vtb  = (bf16*)(ws + 67108864);
  int*  sst  = (int*)(ws + 71303168);
  bf16* Qsb  = Xb;
  bf16* attb = QKVb;

  cvt_f32_bf16<<<dim3(8192), dim3(256), 0, stream>>>(hidden, Xb, 8388608);
  cvt_f32_bf16<<<dim3(4096), dim3(256), 0, stream>>>(Wq, Wqkv, 4194304);
  cvt_f32_bf16<<<dim3(1024), dim3(256), 0, stream>>>(Wk, Wqkv + 4194304, 1048576);
  cvt_f32_bf16<<<dim3(1024), dim3(256), 0, stream>>>(Wv, Wqkv + 5242880, 1048576);
  cvt_f32_bf16<<<dim3(4096), dim3(256), 0, stream>>>(Wo, Wob, 4194304);
  seq_start<<<dim3(32), dim3(256), 0, stream>>>(seq, sst);

  gemm_bt<1><<<dim3(24, 32), dim3(256), 0, stream>>>(Xb, Wqkv, (void*)QKVb, 4096, 3072, 2048);

  qkv_post<<<dim3(4096), dim3(256), 0, stream>>>(QKVb, wpos, Qsb, Ksb, Vtb);

  attn_fwd<<<dim3(1024), dim3(256), 0, stream>>>(Qsb, Ksb, Vtb, sst, attb);

  gemm_bt<0><<<dim3(16, 32), dim3(256), 0, stream>>>(attb, Wob, d_out, 4096, 2048, 2048);
}